// Round 1
// baseline (19053.023 us; speedup 1.0000x reference)
//
#include <hip/hip_runtime.h>
#include <hip/hip_bf16.h>
#include <stdint.h>

typedef __attribute__((ext_vector_type(8))) __bf16 bf16x8;
typedef __attribute__((ext_vector_type(8))) short short8;
typedef __attribute__((ext_vector_type(4))) float f32x4;
typedef __attribute__((ext_vector_type(16))) float f32x16;

#define NB 256
#define NT 201
#define NTS 200
#define NH 512
#define NV 100
#define NG 2048
#define NK2 1024

static __device__ __forceinline__ unsigned short f2bf(float f) {
  union { float f; uint32_t u; } v; v.f = f;
  uint32_t u = v.u;
  return (unsigned short)((u + 0x7fffu + ((u >> 16) & 1u)) >> 16);
}

// ---------------- prep: reorder weights to bf16, fuse biases ----------------
// Wr[l][col=4*j+g][k 0..1023]  (k<512: W_ih row g*512+j ; k>=512: W_hh)
__global__ void prep_kernel(const float* __restrict__ Wih, const float* __restrict__ Whh,
                            const float* __restrict__ bih, const float* __restrict__ bhh,
                            const float* __restrict__ projW, const float* __restrict__ embed,
                            unsigned short* __restrict__ Wr, float* __restrict__ br,
                            unsigned short* __restrict__ WpB, unsigned short* __restrict__ sos)
{
  int idx = blockIdx.x * 256 + threadIdx.x;
  if (idx < 786432) {
    int l = idx >> 18;
    int rem = idx & 262143;
    int col = rem >> 7;
    int ch = rem & 127;
    int g = col & 3, j = col >> 2;
    int srow = g * 512 + j;
    int k0 = ch * 8;
    const float* src = (k0 < 512) ? (Wih + ((size_t)l * NG + srow) * NH + k0)
                                  : (Whh + ((size_t)l * NG + srow) * NH + (k0 - 512));
    union { short8 v; unsigned short u[8]; } o;
#pragma unroll
    for (int q = 0; q < 8; ++q) o.u[q] = f2bf(src[q]);
    *reinterpret_cast<short8*>(Wr + ((size_t)l * NG + col) * NK2 + k0) = o.v;
  } else if (idx < 792576) {
    int e = idx - 786432;
    int l = e >> 11;
    int col = e & 2047;
    int srow = (col & 3) * 512 + (col >> 2);
    br[e] = bih[l * NG + srow] + bhh[l * NG + srow];
  } else if (idx < 799744) {
    int e = idx - 792576;
    int row = e >> 6, sl = e & 63;
    int k0 = sl * 8;
    union { short8 v; unsigned short u[8]; } o;
    if (row < NV) {
      const float* src = projW + (size_t)row * NH + k0;
#pragma unroll
      for (int q = 0; q < 8; ++q) o.u[q] = f2bf(src[q]);
    } else {
#pragma unroll
      for (int q = 0; q < 8; ++q) o.u[q] = 0;
    }
    *reinterpret_cast<short8*>(WpB + (size_t)row * NH + k0) = o.v;
  } else if (idx < 799808) {
    int e = idx - 799744;
    int k0 = e * 8;
    union { short8 v; unsigned short u[8]; } o;
#pragma unroll
    for (int q = 0; q < 8; ++q) o.u[q] = f2bf(embed[NH + k0 + q]); // row 1 = SOS
    *reinterpret_cast<short8*>(sos + k0) = o.v;
  }
}

// ---------------- embedding gather -> bf16 [t][b][h] ----------------
__global__ void embed_kernel(const int* __restrict__ tgt, const float* __restrict__ embed,
                             unsigned short* __restrict__ xemb)
{
  int idx = blockIdx.x * 256 + threadIdx.x;   // 12800*256 == 200*256*64 exactly
  int r = idx >> 6, ch = idx & 63;
  int t = r >> 8, b = r & 255;
  int tok = tgt[b * NT + t + 1];
  const float* src = embed + (size_t)tok * NH + ch * 8;
  union { short8 v; unsigned short u[8]; } o;
#pragma unroll
  for (int q = 0; q < 8; ++q) o.u[q] = f2bf(src[q]);
  *reinterpret_cast<short8*>(xemb + (size_t)r * NH + ch * 8) = o.v;
}

// ---------------- cluster barrier (monotonic counter) ----------------
__device__ __forceinline__ void cluster_bar(unsigned* barc, int tid, unsigned target)
{
  __threadfence();
  __syncthreads();
  if (tid == 0) {
    __hip_atomic_fetch_add(barc, 1u, __ATOMIC_RELEASE, __HIP_MEMORY_SCOPE_AGENT);
    while (__hip_atomic_load(barc, __ATOMIC_ACQUIRE, __HIP_MEMORY_SCOPE_AGENT) < target) {
      __builtin_amdgcn_s_sleep(1);
    }
  }
  __syncthreads();
  __threadfence();
}

// ---------------- persistent LSTM scan ----------------
// grid 256 blocks x 128 thr. cluster c = bid&7 owns samples [32c,32c+32).
// WG wgi = bid>>3 owns gate cols [64*wgi, 64*wgi+64) (= hidden units [16*wgi,+16) x 4 gates)
__global__ __launch_bounds__(128)
void lstm_scan(const unsigned short* __restrict__ Wr, const float* __restrict__ br,
               const unsigned short* __restrict__ xemb, unsigned short* __restrict__ out0,
               unsigned short* __restrict__ out1, const float* __restrict__ feat,
               unsigned short* __restrict__ hbuf, unsigned* __restrict__ bar)
{
  extern __shared__ char lds[];
  const int bid = blockIdx.x;
  const int c = bid & 7, wgi = bid >> 3;
  const int tid = threadIdx.x;
  const int wv = tid >> 6, l = tid & 63;
  const int lm = l & 31, lh = l >> 5;
  const int sampG = c * 32 + lm;
  const int colL = wv * 32 + lm;
  const int colG = wgi * 64 + colL;
  const bool isg = ((colG & 3) == 2);
  const int j = colG >> 2;
  unsigned* barc = bar + c * 32;
  unsigned roundno = 0;
  const int xorr = (colL & 7) << 4;
  const char* wbase = lds + colL * 2048;

  for (int layer = 0; layer < 3; ++layer) {
    // stage this WG's 64 weight rows (K=1024, bf16) with XOR swizzle
    const unsigned short* wsrc = Wr + ((size_t)layer * NG + (size_t)wgi * 64) * NK2;
    for (int e = tid; e < 8192; e += 128) {
      int row = e >> 7, sl = e & 127;
      int byte = row * 2048 + ((sl * 16) ^ ((row & 7) << 4));
      *reinterpret_cast<short8*>(lds + byte) =
          *reinterpret_cast<const short8*>(wsrc + (size_t)row * NK2 + sl * 8);
    }
    const float bias = br[layer * NG + colG];
    float cst[16];
#pragma unroll
    for (int r = 0; r < 16; ++r) cst[r] = 0.f;
    // h0 = feat (bf16) into ping-pong buffer 0 (this WG's hidden slice)
    for (int e = tid; e < 512; e += 128) {
      int s = e >> 4, hh = e & 15;
      size_t o = (size_t)(c * 32 + s) * NH + wgi * 16 + hh;
      hbuf[o] = f2bf(feat[o]);
    }
    cluster_bar(barc, tid, (++roundno) * 32u);

    const unsigned short* xsrc = (layer == 0) ? xemb : ((layer == 1) ? out0 : out1);
    unsigned short* osrc = (layer == 0) ? out0 : ((layer == 1) ? out1 : out0);

    for (int t = 0; t < NTS; ++t) {
      const unsigned short* hr = hbuf + (size_t)(t & 1) * (NB * NH) + (size_t)sampG * NH + lh * 8;
      unsigned short* hw = hbuf + (size_t)((t + 1) & 1) * (NB * NH);
      const unsigned short* xr = xsrc + ((size_t)t * NB + sampG) * NH + lh * 8;
      f32x16 acc0, acc1;
#pragma unroll
      for (int i = 0; i < 16; ++i) { acc0[i] = 0.f; acc1[i] = 0.f; }
#pragma unroll 8
      for (int ks = 0; ks < 32; ++ks) {          // x half (K 0..511)
        bf16x8 a = *reinterpret_cast<const bf16x8*>(xr + ks * 16);
        bf16x8 bfr = *reinterpret_cast<const bf16x8*>(wbase + (((ks * 32) + lh * 16) ^ xorr));
        acc0 = __builtin_amdgcn_mfma_f32_32x32x16_bf16(a, bfr, acc0, 0, 0, 0);
      }
#pragma unroll 8
      for (int ks = 0; ks < 32; ++ks) {          // h half (K 512..1023)
        bf16x8 a = *reinterpret_cast<const bf16x8*>(hr + ks * 16);
        bf16x8 bfr = *reinterpret_cast<const bf16x8*>(wbase + ((1024 + (ks * 32) + lh * 16) ^ xorr));
        acc1 = __builtin_amdgcn_mfma_f32_32x32x16_bf16(a, bfr, acc1, 0, 0, 0);
      }
      // epilogue: bias + nonlinearity; quad lanes hold (i,f,g,o) of one hidden unit
#pragma unroll
      for (int r = 0; r < 16; ++r) {
        float x = acc0[r] + acc1[r] + bias;
        float xx = isg ? (x + x) : x;
        float sgm = 1.f / (1.f + __expf(-xx));
        float a = isg ? (sgm + sgm - 1.f) : sgm;
        float f1 = __shfl_xor(a, 1);
        float u2 = __shfl_xor(a, 2);
        float o3 = __shfl_xor(a, 3);
        float cn = __builtin_fmaf(f1, cst[r], a * u2);  // valid on lanes l&3==0
        cst[r] = cn;
        float e2 = __expf(-2.f * cn);
        float th = 2.f / (1.f + e2) - 1.f;
        float hv = o3 * th;
        if ((l & 3) == 0) {
          int m = (r & 3) + 8 * (r >> 2) + 4 * lh;  // C-row = local sample
          int sg = c * 32 + m;
          unsigned short hb = f2bf(hv);
          hw[(size_t)sg * NH + j] = hb;
          osrc[((size_t)t * NB + sg) * NH + j] = hb;
        }
      }
      cluster_bar(barc, tid, (++roundno) * 32u);
    }
  }
}

// ---------------- projection: per-b  C[v][t] = projW @ res_b^T + pb ----------------
__global__ __launch_bounds__(256)
void proj_kernel(const unsigned short* __restrict__ WpB, const unsigned short* __restrict__ outL,
                 const unsigned short* __restrict__ sos, const float* __restrict__ pb,
                 float* __restrict__ dout)
{
  extern __shared__ char plds[];
  const int b = blockIdx.x, tid = threadIdx.x;
  const int wv = tid >> 6, l = tid & 63;
  const int ln = l & 15, lk = l >> 4;
  for (int e = tid; e < 7168; e += 256) {     // stage WpB (112 x 512 bf16), swizzled
    int row = e >> 6, sl = e & 63;
    int byte = row * 1024 + ((sl * 16) ^ ((row & 7) << 4));
    *reinterpret_cast<short8*>(plds + byte) =
        *reinterpret_cast<const short8*>(WpB + (size_t)row * NH + sl * 8);
  }
  __syncthreads();
  for (int nt = wv; nt < 13; nt += 4) {
    int tt = nt * 16 + ln;
    const unsigned short* rowp = (tt == 0 || tt > 200) ? sos
        : outL + ((size_t)(tt - 1) * NB + b) * NH;
    bf16x8 Bfr[16];
#pragma unroll
    for (int ks = 0; ks < 16; ++ks)
      Bfr[ks] = *reinterpret_cast<const bf16x8*>(rowp + ks * 32 + lk * 8);
    for (int mt = 0; mt < 7; ++mt) {
      f32x4 acc;
#pragma unroll
      for (int i = 0; i < 4; ++i) acc[i] = 0.f;
#pragma unroll
      for (int ks = 0; ks < 16; ++ks) {
        int row = mt * 16 + ln;
        int byte = row * 1024 + (((ks * 64) + lk * 16) ^ ((row & 7) << 4));
        bf16x8 a = *reinterpret_cast<const bf16x8*>(plds + byte);
        acc = __builtin_amdgcn_mfma_f32_16x16x32_bf16(a, Bfr[ks], acc, 0, 0, 0);
      }
#pragma unroll
      for (int r = 0; r < 4; ++r) {
        int v = mt * 16 + lk * 4 + r;
        if (v < NV && tt < NT)
          dout[((size_t)b * NV + v) * NT + tt] = acc[r] + pb[v];
      }
    }
  }
}

extern "C" void kernel_launch(void* const* d_in, const int* in_sizes, int n_in,
                              void* d_out, int out_size, void* d_ws, size_t ws_size,
                              hipStream_t stream)
{
  const float* feat  = (const float*)d_in[0];
  const int*   tgt   = (const int*)  d_in[1];
  const float* embed = (const float*)d_in[2];
  const float* Wih   = (const float*)d_in[3];
  const float* Whh   = (const float*)d_in[4];
  const float* bih   = (const float*)d_in[5];
  const float* bhh   = (const float*)d_in[6];
  const float* projW = (const float*)d_in[7];
  const float* pb    = (const float*)d_in[8];
  float* out = (float*)d_out;

  char* ws = (char*)d_ws;
  size_t off = 0;
  auto alloc = [&](size_t bytes) {
    char* p = ws + off;
    off = (off + bytes + 255) & ~(size_t)255;
    return p;
  };
  unsigned short* Wr   = (unsigned short*)alloc((size_t)3 * NG * NK2 * 2);   // 12.58 MB
  float*          br   = (float*)         alloc((size_t)3 * NG * 4);
  unsigned short* WpB  = (unsigned short*)alloc((size_t)112 * NH * 2);
  unsigned short* sos  = (unsigned short*)alloc((size_t)NH * 2);
  unsigned short* xemb = (unsigned short*)alloc((size_t)NTS * NB * NH * 2);  // 52.4 MB (reused as out1)
  unsigned short* out0 = (unsigned short*)alloc((size_t)NTS * NB * NH * 2);  // 52.4 MB
  unsigned short* hbuf = (unsigned short*)alloc((size_t)2 * NB * NH * 2);
  unsigned*       bar  = (unsigned*)      alloc(1024);
  unsigned short* out1 = xemb;  // layer-1 output overwrites embeddings (dead by then)

  hipMemsetAsync(bar, 0, 1024, stream);

  hipFuncSetAttribute((const void*)lstm_scan, hipFuncAttributeMaxDynamicSharedMemorySize, 131072);
  hipFuncSetAttribute((const void*)proj_kernel, hipFuncAttributeMaxDynamicSharedMemorySize, 114688);

  prep_kernel<<<3125, 256, 0, stream>>>(Wih, Whh, bih, bhh, projW, embed, Wr, br, WpB, sos);
  embed_kernel<<<12800, 256, 0, stream>>>(tgt, embed, xemb);
  lstm_scan<<<256, 128, 131072, stream>>>(Wr, br, xemb, out0, out1, feat, hbuf, bar);
  proj_kernel<<<256, 256, 114688, stream>>>(WpB, out0, sos, pb, out);
}

// Round 3
// 4736.482 us; speedup vs baseline: 4.0226x; 4.0226x over previous
//
#include <hip/hip_runtime.h>
#include <hip/hip_bf16.h>
#include <stdint.h>

typedef __attribute__((ext_vector_type(8))) __bf16 bf16x8;
typedef __attribute__((ext_vector_type(8))) short short8;
typedef __attribute__((ext_vector_type(4))) float f32x4;
typedef __attribute__((ext_vector_type(16))) float f32x16;

#define NB 256
#define NT 201
#define NTS 200
#define NH 512
#define NV 100
#define NG 2048
#define NK2 1024

static __device__ __forceinline__ unsigned short f2bf(float f) {
  union { float f; uint32_t u; } v; v.f = f;
  uint32_t u = v.u;
  return (unsigned short)((u + 0x7fffu + ((u >> 16) & 1u)) >> 16);
}

// ---------------- prep: reorder weights to bf16, fuse biases, hfeat ----------------
__global__ void prep_kernel(const float* __restrict__ Wih, const float* __restrict__ Whh,
                            const float* __restrict__ bih, const float* __restrict__ bhh,
                            const float* __restrict__ projW, const float* __restrict__ embed,
                            const float* __restrict__ feat,
                            unsigned short* __restrict__ Wr, float* __restrict__ br,
                            unsigned short* __restrict__ WpB, unsigned short* __restrict__ sos,
                            unsigned short* __restrict__ hfeat)
{
  int idx = blockIdx.x * 256 + threadIdx.x;
  if (idx < 786432) {
    int l = idx >> 18;
    int rem = idx & 262143;
    int col = rem >> 7;
    int ch = rem & 127;
    int g = col & 3, j = col >> 2;
    int srow = g * 512 + j;
    int k0 = ch * 8;
    const float* src = (k0 < 512) ? (Wih + ((size_t)l * NG + srow) * NH + k0)
                                  : (Whh + ((size_t)l * NG + srow) * NH + (k0 - 512));
    union { short8 v; unsigned short u[8]; } o;
#pragma unroll
    for (int q = 0; q < 8; ++q) o.u[q] = f2bf(src[q]);
    *reinterpret_cast<short8*>(Wr + ((size_t)l * NG + col) * NK2 + k0) = o.v;
  } else if (idx < 792576) {
    int e = idx - 786432;
    int l = e >> 11;
    int col = e & 2047;
    int srow = (col & 3) * 512 + (col >> 2);
    br[e] = bih[l * NG + srow] + bhh[l * NG + srow];
  } else if (idx < 799744) {
    int e = idx - 792576;
    int row = e >> 6, sl = e & 63;
    int k0 = sl * 8;
    union { short8 v; unsigned short u[8]; } o;
    if (row < NV) {
      const float* src = projW + (size_t)row * NH + k0;
#pragma unroll
      for (int q = 0; q < 8; ++q) o.u[q] = f2bf(src[q]);
    } else {
#pragma unroll
      for (int q = 0; q < 8; ++q) o.u[q] = 0;
    }
    *reinterpret_cast<short8*>(WpB + (size_t)row * NH + k0) = o.v;
  } else if (idx < 799808) {
    int e = idx - 799744;
    int k0 = e * 8;
    union { short8 v; unsigned short u[8]; } o;
#pragma unroll
    for (int q = 0; q < 8; ++q) o.u[q] = f2bf(embed[NH + k0 + q]); // row 1 = SOS
    *reinterpret_cast<short8*>(sos + k0) = o.v;
  } else if (idx < 816192) {
    int e = idx - 799808;          // 16384 items: 256 samples x 64 chunks
    int k0 = e * 8;                // flat over 256*512
    union { short8 v; unsigned short u[8]; } o;
#pragma unroll
    for (int q = 0; q < 8; ++q) o.u[q] = f2bf(feat[k0 + q]);
    *reinterpret_cast<short8*>(hfeat + k0) = o.v;
  }
}

// ---------------- embedding gather -> bf16 [t][b][h] ----------------
__global__ void embed_kernel(const int* __restrict__ tgt, const float* __restrict__ embed,
                             unsigned short* __restrict__ xemb)
{
  int idx = blockIdx.x * 256 + threadIdx.x;   // 12800*256 == 200*256*64 exactly
  int r = idx >> 6, ch = idx & 63;
  int t = r >> 8, b = r & 255;
  int tok = tgt[b * NT + t + 1];
  const float* src = embed + (size_t)tok * NH + ch * 8;
  union { short8 v; unsigned short u[8]; } o;
#pragma unroll
  for (int q = 0; q < 8; ++q) o.u[q] = f2bf(src[q]);
  *reinterpret_cast<short8*>(xemb + (size_t)r * NH + ch * 8) = o.v;
}

// ---------------- asm helpers ----------------
// DEV=true: device-scope (sc1) -> coherent via LLC/fabric (memory-side, never stale)
template<int I, bool DEV>
struct Iss {
  static __device__ __forceinline__ void go(bf16x8* f, const unsigned short* p) {
    if constexpr (DEV)
      asm volatile("global_load_dwordx4 %0, %1, off offset:%c2 sc1"
                   : "=v"(f[I]) : "v"(p), "i"(I * 32));
    else
      asm volatile("global_load_dwordx4 %0, %1, off offset:%c2"
                   : "=v"(f[I]) : "v"(p), "i"(I * 32));
    Iss<I + 1, DEV>::go(f, p);
  }
};
template<bool DEV>
struct Iss<32, DEV> { static __device__ __forceinline__ void go(bf16x8*, const unsigned short*) {} };

static __device__ __forceinline__ unsigned ld_poll(const unsigned* p) {
  unsigned r;
  asm volatile("global_load_dword %0, %1, off sc1\n\ts_waitcnt vmcnt(0)"
               : "=v"(r) : "v"(p) : "memory");
  return r;
}

static __device__ __forceinline__ void sig_add(unsigned* p) {
  unsigned one = 1u;
  asm volatile("global_atomic_add %0, %1, off sc1" :: "v"(p), "v"(one) : "memory");
}

static __device__ __forceinline__ void stsc1(unsigned short* p, unsigned short v) {
  asm volatile("global_store_short %0, %1, off sc1" :: "v"(p), "v"(v) : "memory");
}

#define MFMA __builtin_amdgcn_mfma_f32_32x32x16_bf16
#define GW(N) do { asm volatile("s_waitcnt vmcnt(" #N ")"); \
                   __builtin_amdgcn_sched_barrier(0); } while (0)
#define VMCNT0 asm volatile("s_waitcnt vmcnt(0)" ::: "memory")

// ---------------- persistent LSTM scan ----------------
// 256 WGs x 128 thr, 1 WG/CU (128KB LDS). Logical cluster c = bid&7 (32 WGs),
// samples [32c, 32c+32). WG wgi = bid>>3 owns gate cols [64*wgi, +64).
// All cross-WG state (h rows, barrier) uses device-scope sc1 ops -> coherent
// at the fabric/LLC regardless of which XCDs the WGs land on. No cache
// maintenance anywhere in the hot loop.
__global__ __launch_bounds__(128, 1)
void lstm_scan(const unsigned short* __restrict__ Wr, const float* __restrict__ br,
               const unsigned short* __restrict__ xemb, unsigned short* __restrict__ out0,
               unsigned short* __restrict__ out1, const unsigned short* __restrict__ hfeat,
               unsigned* __restrict__ bar)
{
  extern __shared__ char lds[];
  const int bid = blockIdx.x;
  const int c = bid & 7, wgi = bid >> 3;
  const int tid = threadIdx.x;
  const int wv = tid >> 6, l = tid & 63;
  const int lm = l & 31, lh = l >> 5;
  const int lh16 = lh * 16, lh8 = lh * 8;
  const int sampG = c * 32 + lm;
  const int colL = wv * 32 + lm;
  const int colG = wgi * 64 + colL;
  const bool isg = ((colG & 3) == 2);
  const int j = colG >> 2;
  const int xorr = (colL & 7) << 4;
  const char* wbase = lds + colL * 2048;
  unsigned* barc = bar + c * 64;

  const unsigned short* xs_[3] = { xemb, out0, out1 };
  unsigned short* os_[3] = { out0, out1, out0 };

  bf16x8 f[32];                 // time-shared between x-phase and h-phase
  f32x16 a0a, a0b, a1a, a1b;

#define XM(ks) \
  a0a = MFMA(f[ks],     *(const bf16x8*)(wbase + (((ks)*32 + lh16) ^ xorr)),     a0a, 0,0,0); \
  a0b = MFMA(f[(ks)+1], *(const bf16x8*)(wbase + ((((ks)+1)*32 + lh16) ^ xorr)), a0b, 0,0,0);
#define HM(ks) \
  a1a = MFMA(f[ks],     *(const bf16x8*)(wbase + ((1024 + (ks)*32 + lh16) ^ xorr)),     a1a, 0,0,0); \
  a1b = MFMA(f[(ks)+1], *(const bf16x8*)(wbase + ((1024 + ((ks)+1)*32 + lh16) ^ xorr)), a1b, 0,0,0);

  for (int layer = 0; layer < 3; ++layer) {
    __syncthreads();            // all waves done with previous layer's weights
    if (layer == 2) __threadfence();  // invalidate stale xemb(=out1) lines in L1/L2
    const unsigned short* wsrc = Wr + ((size_t)layer * NG + (size_t)wgi * 64) * NK2;
    for (int e = tid; e < 8192; e += 128) {
      int row = e >> 7, sl = e & 127;
      int byte = row * 2048 + ((sl * 16) ^ ((row & 7) << 4));
      *reinterpret_cast<short8*>(lds + byte) =
          *reinterpret_cast<const short8*>(wsrc + (size_t)row * NK2 + sl * 8);
    }
    __syncthreads();

    const float bias = br[layer * NG + colG];
    float cst[16];
#pragma unroll
    for (int r = 0; r < 16; ++r) cst[r] = 0.f;

    const unsigned short* xsrc = xs_[layer];
    unsigned short* osrc = os_[layer];

    // prologue: x-half for t=0 (cached loads; xsrc rows are stable by now)
    Iss<0, false>::go(f, xsrc + (size_t)sampG * NH + lh8);
#pragma unroll
    for (int i = 0; i < 16; ++i) { a0a[i] = 0.f; a0b[i] = 0.f; }
    GW(24); XM(0) XM(2) XM(4) XM(6)
    GW(16); XM(8) XM(10) XM(12) XM(14)
    GW(8);  XM(16) XM(18) XM(20) XM(22)
    GW(0);  XM(24) XM(26) XM(28) XM(30)

    for (int t = 0; t < NTS; ++t) {
      if (t) {                                         // wait for h(t)=osrc[t-1]
        unsigned tgt = 32u * (unsigned)(layer * NTS + t);
        while (ld_poll(barc) < tgt) {}
      }
      const unsigned short* hr = (t == 0)
          ? (hfeat + (size_t)sampG * NH + lh8)
          : (osrc + ((size_t)(t - 1) * NB + sampG) * NH + lh8);
      Iss<0, true>::go(f, hr);                         // sc1: race-fresh via fabric
#pragma unroll
      for (int i = 0; i < 16; ++i) { a1a[i] = 0.f; a1b[i] = 0.f; }
      GW(24); HM(0) HM(2) HM(4) HM(6)
      GW(16); HM(8) HM(10) HM(12) HM(14)
      GW(8);  HM(16) HM(18) HM(20) HM(22)
      GW(0);  HM(24) HM(26) HM(28) HM(30)

      unsigned short* orow = osrc + (size_t)t * NB * NH;
#pragma unroll
      for (int r = 0; r < 16; ++r) {
        float x = a0a[r] + a0b[r] + a1a[r] + a1b[r] + bias;
        float xx = isg ? (x + x) : x;
        float sgm = 1.f / (1.f + __expf(-xx));
        float a = isg ? (sgm + sgm - 1.f) : sgm;
        float f1 = __shfl_xor(a, 1);
        float u2 = __shfl_xor(a, 2);
        float o3 = __shfl_xor(a, 3);
        float cn = __builtin_fmaf(f1, cst[r], a * u2);  // valid on lanes l&3==0
        cst[r] = cn;
        float e2 = __expf(-2.f * cn);
        float th = 2.f / (1.f + e2) - 1.f;
        float hv = o3 * th;
        if ((l & 3) == 0) {
          int m = (r & 3) + 8 * (r >> 2) + 4 * lh;      // C-row = local sample
          stsc1(orow + (size_t)(c * 32 + m) * NH + j, f2bf(hv));
        }
      }

      VMCNT0;                                          // own wave's h-stores drained
      __syncthreads();                                 // both waves drained
      if (tid == 0) sig_add(barc);                     // 1 signal per WG per round

      if (t < NTS - 1) {                               // x-half for t+1 hides barrier
        Iss<0, false>::go(f, xsrc + ((size_t)(t + 1) * NB + sampG) * NH + lh8);
#pragma unroll
        for (int i = 0; i < 16; ++i) { a0a[i] = 0.f; a0b[i] = 0.f; }
        GW(24); XM(0) XM(2) XM(4) XM(6)
        GW(16); XM(8) XM(10) XM(12) XM(14)
        GW(8);  XM(16) XM(18) XM(20) XM(22)
        GW(0);  XM(24) XM(26) XM(28) XM(30)
      }
    }
  }
}

// ---------------- projection: per-b  C[v][t] = projW @ res_b^T + pb ----------------
__global__ __launch_bounds__(256)
void proj_kernel(const unsigned short* __restrict__ WpB, const unsigned short* __restrict__ outL,
                 const unsigned short* __restrict__ sos, const float* __restrict__ pb,
                 float* __restrict__ dout)
{
  extern __shared__ char plds[];
  const int b = blockIdx.x, tid = threadIdx.x;
  const int wv = tid >> 6, l = tid & 63;
  const int ln = l & 15, lk = l >> 4;
  for (int e = tid; e < 7168; e += 256) {     // stage WpB (112 x 512 bf16), swizzled
    int row = e >> 6, sl = e & 63;
    int byte = row * 1024 + ((sl * 16) ^ ((row & 7) << 4));
    *reinterpret_cast<short8*>(plds + byte) =
        *reinterpret_cast<const short8*>(WpB + (size_t)row * NH + sl * 8);
  }
  __syncthreads();
  for (int nt = wv; nt < 13; nt += 4) {
    int tt = nt * 16 + ln;
    const unsigned short* rowp = (tt == 0 || tt > 200) ? sos
        : outL + ((size_t)(tt - 1) * NB + b) * NH;
    bf16x8 Bfr[16];
#pragma unroll
    for (int ks = 0; ks < 16; ++ks)
      Bfr[ks] = *reinterpret_cast<const bf16x8*>(rowp + ks * 32 + lk * 8);
    for (int mt = 0; mt < 7; ++mt) {
      f32x4 acc;
#pragma unroll
      for (int i = 0; i < 4; ++i) acc[i] = 0.f;
#pragma unroll
      for (int ks = 0; ks < 16; ++ks) {
        int row = mt * 16 + ln;
        int byte = row * 1024 + (((ks * 64) + lk * 16) ^ ((row & 7) << 4));
        bf16x8 a = *reinterpret_cast<const bf16x8*>(plds + byte);
        acc = __builtin_amdgcn_mfma_f32_16x16x32_bf16(a, Bfr[ks], acc, 0, 0, 0);
      }
#pragma unroll
      for (int r = 0; r < 4; ++r) {
        int v = mt * 16 + lk * 4 + r;
        if (v < NV && tt < NT)
          dout[((size_t)b * NV + v) * NT + tt] = acc[r] + pb[v];
      }
    }
  }
}

extern "C" void kernel_launch(void* const* d_in, const int* in_sizes, int n_in,
                              void* d_out, int out_size, void* d_ws, size_t ws_size,
                              hipStream_t stream)
{
  const float* feat  = (const float*)d_in[0];
  const int*   tgt   = (const int*)  d_in[1];
  const float* embed = (const float*)d_in[2];
  const float* Wih   = (const float*)d_in[3];
  const float* Whh   = (const float*)d_in[4];
  const float* bih   = (const float*)d_in[5];
  const float* bhh   = (const float*)d_in[6];
  const float* projW = (const float*)d_in[7];
  const float* pb    = (const float*)d_in[8];
  float* out = (float*)d_out;

  char* ws = (char*)d_ws;
  size_t off = 0;
  auto alloc = [&](size_t bytes) {
    char* p = ws + off;
    off = (off + bytes + 255) & ~(size_t)255;
    return p;
  };
  unsigned short* Wr    = (unsigned short*)alloc((size_t)3 * NG * NK2 * 2);   // 12.58 MB
  float*          br    = (float*)         alloc((size_t)3 * NG * 4);
  unsigned short* WpB   = (unsigned short*)alloc((size_t)112 * NH * 2);
  unsigned short* sos   = (unsigned short*)alloc((size_t)NH * 2);
  unsigned short* hfeat = (unsigned short*)alloc((size_t)NB * NH * 2);        // 256 KB
  unsigned short* xemb  = (unsigned short*)alloc((size_t)NTS * NB * NH * 2);  // 52.4 MB
  unsigned short* out0  = (unsigned short*)alloc((size_t)NTS * NB * NH * 2);  // 52.4 MB
  unsigned*       bar   = (unsigned*)      alloc(2048);   // 8 clusters * 64B-spaced
  unsigned short* out1 = xemb;   // layer-1 output overwrites embeddings (dead by then)

  hipMemsetAsync(bar, 0, 2048, stream);

  hipFuncSetAttribute((const void*)lstm_scan, hipFuncAttributeMaxDynamicSharedMemorySize, 131072);
  hipFuncSetAttribute((const void*)proj_kernel, hipFuncAttributeMaxDynamicSharedMemorySize, 114688);

  prep_kernel<<<3189, 256, 0, stream>>>(Wih, Whh, bih, bhh, projW, embed, feat,
                                        Wr, br, WpB, sos, hfeat);
  embed_kernel<<<12800, 256, 0, stream>>>(tgt, embed, xemb);
  lstm_scan<<<256, 128, 131072, stream>>>(Wr, br, xemb, out0, out1, hfeat, bar);
  proj_kernel<<<256, 256, 114688, stream>>>(WpB, out0, sos, pb, out);
}